// Round 6
// baseline (218.069 us; speedup 1.0000x reference)
//
#include <hip/hip_runtime.h>
#include <math.h>

// SSIM on MI355X, round 12: round-11 fused-finalize design, with the counter
// zeroed via hipMemcpyAsync(H2D, 4B, static host zero) -- the stream-side op
// the harness explicitly endorses in kernel_launch -- instead of
// hipMemsetAsync (suspected graph-capture tripwire in round 11's container
// failure). Everything else identical:
//   - packed image-pair math (v_pk_fma_f32 via <2 x float>), 58x4 strips,
//     4 waves/block, LDS exactly 40960 B -> 4 blocks/CU
//   - threadfence last-block reduction replaces the second launch; the last
//     block replicates the old finalize's summation order exactly
//     (stride-256, f64, 64-wide shuffle) -> bit-identical result.

#define WI 320
#define HI 320
#define NI 64
#define NZ (NI / 2)             // 32 image pairs
#define TWO 58                  // output cols per x-tile (64 loaded incl. halo)
#define GXD 6                   // ceil(320/58)
#define GYD 20                  // 16 output rows per block (4 waves x 4 rows)
#define NBLK (GXD * GYD * NZ)   // 3840 blocks
#define NPART (2 * NBLK)        // 7680 partial floats (2 images per block)
#define NPIX ((double)NI * WI * HI)
#define IMG (WI * HI)
#define WREG (5 * 4 * 64)       // per-wave LDS float2 count: 1280 (10240 B)

typedef float v2f __attribute__((ext_vector_type(2)));
typedef float v4f __attribute__((ext_vector_type(4)));

struct W7 { float w[7]; };

// One wave, one 58x4 strip of an image PAIR. XM: 0=left tile, 1=interior,
// 2=right. YI: all 10 input rows in-bounds. Returns packed SSIM partials.
template <bool YI, int XM>
__device__ __forceinline__ v2f wave_task(
    const float* __restrict__ X0, const float* __restrict__ X1,
    const float* __restrict__ Y0, const float* __restrict__ Y1,
    const W7& wv, v2f* __restrict__ vb, int x0, int y0, int lane)
{
    const int gx   = x0 + lane - 3;
    const bool xok = (XM == 1) || (XM == 0 ? (gx >= 0) : (gx < WI));

    // ---- 40 coalesced dword loads (lane = consecutive col), zero-pad OOB ----
    v2f xr[10], yr[10];
#pragma unroll
    for (int j = 0; j < 10; ++j) {
        const int gy  = y0 + j - 3;
        const bool ok = xok && (YI || ((unsigned)gy < (unsigned)HI));
        v2f xv = {0.f, 0.f}, yv = {0.f, 0.f};
        if (ok) {
            const int idx = gy * WI + gx;
            xv.x = X0[idx]; xv.y = X1[idx];
            yv.x = Y0[idx]; yv.y = Y1[idx];
        }
        xr[j] = xv; yr[j] = yv;
    }

    // ---- vertical 7-tap, 5 channels x 4 rows, packed over the image pair ----
    v2f acc[5][4];
#pragma unroll
    for (int ch = 0; ch < 5; ++ch)
#pragma unroll
        for (int r = 0; r < 4; ++r) acc[ch][r] = (v2f){0.f, 0.f};
#pragma unroll
    for (int j = 0; j < 10; ++j) {
        const v2f xv = xr[j], yv = yr[j];
        const v2f pxx = xv * xv, pyy = yv * yv, pxy = xv * yv;
#pragma unroll
        for (int r = 0; r < 4; ++r) {
            const int d = j - r;                 // compile-time predicate
            if (d >= 0 && d < 7) {
                const v2f w2 = {wv.w[d], wv.w[d]};
                acc[0][r] = __builtin_elementwise_fma(w2, xv,  acc[0][r]);
                acc[1][r] = __builtin_elementwise_fma(w2, yv,  acc[1][r]);
                acc[2][r] = __builtin_elementwise_fma(w2, pxx, acc[2][r]);
                acc[3][r] = __builtin_elementwise_fma(w2, pyy, acc[3][r]);
                acc[4][r] = __builtin_elementwise_fma(w2, pxy, acc[4][r]);
            }
        }
    }
    // 20 b64 writes to this wave's private region; uniform 4 words/bank = free.
#pragma unroll
    for (int ch = 0; ch < 5; ++ch)
#pragma unroll
        for (int r = 0; r < 4; ++r)
            vb[ch * 256 + r * 64 + lane] = acc[ch][r];

    __builtin_amdgcn_wave_barrier();   // scheduling fence; lgkmcnt orders the data

    // ---- horizontal 7-tap + SSIM. lane -> (row, 4 consecutive out cols) ----
    v2f lsum = {0.f, 0.f};
    const int row = lane >> 4;
    const int xg  = (lane & 15) << 2;          // 0,4,...,60
    if (xg < TWO) {                            // xg==60 lanes idle
        // Need f2[0..9] (j<=3, d<=6). f2[8..9] only matter for xg<=52 (at
        // xg=56 valid outputs j<2 use f2[0..7]); clamp that read in-bounds.
        const int xg3 = (xg > 52) ? 52 : xg;
        const v2f zero = {0.f, 0.f};
        v2f m[4][5];
#pragma unroll
        for (int ch = 0; ch < 5; ++ch) {
            const v2f* base = &vb[ch * 256 + row * 64];
            const v4f q0 = *(const v4f*)&base[xg];
            const v4f q1 = *(const v4f*)&base[xg + 2];
            const v4f q2 = *(const v4f*)&base[xg + 4];
            const v4f q3 = *(const v4f*)&base[xg + 6];
            const v4f q4 = *(const v4f*)&base[xg3 + 8];
            const v2f f2[10] = {
                {q0.x,q0.y},{q0.z,q0.w},{q1.x,q1.y},{q1.z,q1.w},
                {q2.x,q2.y},{q2.z,q2.w},{q3.x,q3.y},{q3.z,q3.w},
                {q4.x,q4.y},{q4.z,q4.w}};
#pragma unroll
            for (int j = 0; j < 4; ++j) {
                v2f s = zero;
#pragma unroll
                for (int d = 0; d < 7; ++d) {
                    const v2f w2 = {wv.w[d], wv.w[d]};
                    s = __builtin_elementwise_fma(w2, f2[j + d], s);
                }
                m[j][ch] = s;
            }
        }
#pragma unroll
        for (int j = 0; j < 4; ++j) {
            const v2f mx = m[j][0], my = m[j][1];
            const v2f mxsq = mx * mx;
            const v2f mysq = my * my;
            const v2f mxy  = mx * my;
            const v2f vx   = (m[j][2] - mxsq) * 1.0208333333333333f;
            const v2f vy   = (m[j][3] - mysq) * 1.0208333333333333f;
            const v2f vxy  = (m[j][4] - mxy)  * 1.0208333333333333f;
            const v2f num  = (2.f * mxy + 0.0004f) * (2.f * vxy + 0.0036f);
            const v2f den  = (mxsq + mysq + 0.0004f) * (vx + vy + 0.0036f);
            v2f rden;
            rden.x = __builtin_amdgcn_rcpf(den.x);
            rden.y = __builtin_amdgcn_rcpf(den.y);
            const v2f term = num * rden;
            const bool valid = (xg + j < TWO) && (XM != 2 || x0 + xg + j < WI);
            lsum += valid ? term : zero;
        }
    }
    return lsum;
}

__global__ __launch_bounds__(256, 4) void ssim_kernel(
    const float* __restrict__ X, const float* __restrict__ Y,
    W7 wv, float* __restrict__ partial, unsigned* __restrict__ counter,
    float* __restrict__ out)
{
    __shared__ __align__(16) v2f vbuf[4 * WREG];   // exactly 40960 B -> 4 blocks/CU

    const int tid  = threadIdx.x;
    const int lane = tid & 63;
    const int w    = tid >> 6;
    const int x0   = blockIdx.x * TWO;
    const int y0   = blockIdx.y * 16 + w * 4;  // first output row of this wave
    const float* __restrict__ X0 = X + (size_t)(2 * blockIdx.z) * IMG;
    const float* __restrict__ X1 = X0 + IMG;
    const float* __restrict__ Y0 = Y + (size_t)(2 * blockIdx.z) * IMG;
    const float* __restrict__ Y1 = Y0 + IMG;
    v2f* vb = vbuf + w * WREG;

    const bool yi = (y0 >= 3) && (y0 <= HI - 7);  // all 10 input rows in-bounds
    const int  xm = (blockIdx.x == 0) ? 0 : ((blockIdx.x == GXD - 1) ? 2 : 1);

    v2f lsum;
    if (yi) {
        if      (xm == 0) lsum = wave_task<true, 0>(X0, X1, Y0, Y1, wv, vb, x0, y0, lane);
        else if (xm == 1) lsum = wave_task<true, 1>(X0, X1, Y0, Y1, wv, vb, x0, y0, lane);
        else              lsum = wave_task<true, 2>(X0, X1, Y0, Y1, wv, vb, x0, y0, lane);
    } else {
        if      (xm == 0) lsum = wave_task<false, 0>(X0, X1, Y0, Y1, wv, vb, x0, y0, lane);
        else if (xm == 1) lsum = wave_task<false, 1>(X0, X1, Y0, Y1, wv, vb, x0, y0, lane);
        else              lsum = wave_task<false, 2>(X0, X1, Y0, Y1, wv, vb, x0, y0, lane);
    }

    // ---- block reduction: wave shuffle -> own (consumed) vbuf slot ----
#pragma unroll
    for (int off = 32; off > 0; off >>= 1) {
        lsum.x += __shfl_down(lsum.x, off, 64);
        lsum.y += __shfl_down(lsum.y, off, 64);
    }
    if (lane == 0) vb[0] = lsum;   // wave w writes only its own (consumed) region
    __syncthreads();

    // ---- fused finalize: threadfence last-block reduction ----
    float* scratch = (float*)vbuf;            // vbuf fully consumed past here
    if (tid == 0) {
        const int bid = (blockIdx.z * GYD + blockIdx.y) * GXD + blockIdx.x;
        const v2f t = (vbuf[0] + vbuf[WREG]) + (vbuf[2 * WREG] + vbuf[3 * WREG]);
        partial[2 * bid]     = t.x;
        partial[2 * bid + 1] = t.y;
        __threadfence();                       // release: partials visible device-wide
        const unsigned old = atomicAdd(counter, 1u);
        scratch[2] = (old == NBLK - 1) ? 1.f : 0.f;
    }
    __syncthreads();
    if (scratch[2] != 0.f) {                   // last block: do the old finalize
        __threadfence();                       // acquire: see all partials
        double* ws2 = (double*)((char*)vbuf + 1024);  // consumed region, 16-aligned
        double s = 0.0;
        for (int i = tid; i < NPART; i += 256) s += (double)partial[i];
#pragma unroll
        for (int off = 32; off > 0; off >>= 1)
            s += __shfl_down(s, off, 64);
        if ((tid & 63) == 0) ws2[tid >> 6] = s;
        __syncthreads();
        if (tid == 0)
            out[0] = (float)(1.0 - ((ws2[0] + ws2[1]) + (ws2[2] + ws2[3])) / NPIX);
    }
}

extern "C" void kernel_launch(void* const* d_in, const int* in_sizes, int n_in,
                              void* d_out, int out_size, void* d_ws, size_t ws_size,
                              hipStream_t stream) {
    const float* X = (const float*)d_in[0];
    const float* Y = (const float*)d_in[1];
    // Exact 1D Gaussian weights in fp64 (7x7 window = outer product).
    W7 wv;
    {
        double g[7], s = 0.0;
        for (int i = 0; i < 7; ++i) {
            double x = (double)(i - 3);
            g[i] = exp(-(x * x) / (2.0 * 1.5 * 1.5));
            s += g[i];
        }
        for (int i = 0; i < 7; ++i) wv.w[i] = (float)(g[i] / s);
    }

    unsigned* counter = (unsigned*)d_ws;          // 4 B at offset 0
    float* partial = (float*)d_ws + 64;           // byte offset 256, 7680 floats

    // d_ws is poisoned every iteration -> counter must be re-zeroed.
    // hipMemcpyAsync is the harness-endorsed stream op for kernel_launch
    // (static host source: persists across async graph replays).
    static const unsigned h_zero = 0u;
    hipMemcpyAsync(counter, &h_zero, sizeof(unsigned),
                   hipMemcpyHostToDevice, stream);

    dim3 grid(GXD, GYD, NZ);
    ssim_kernel<<<grid, 256, 0, stream>>>(X, Y, wv, partial, counter, (float*)d_out);
}

// Round 7
// 107.304 us; speedup vs baseline: 2.0323x; 2.0323x over previous
//
#include <hip/hip_runtime.h>
#include <math.h>

// SSIM on MI355X, round 13: round-10 two-kernel structure (packed image-pair
// v_pk_fma_f32 math, 58x4 strips, 4 waves/block, LDS 40960 B = 4 blocks/CU)
// + XOR row-swizzle on the LDS transpose buffer.
// Round-12 lesson (ABANDONED): fused last-block finalize = per-block
// __threadfence() = per-block L2 writeback on non-coherent-XCD CDNA4 ->
// kernel 14 -> 150 us. Two launches are structurally cheaper here.
// New fix: horizontal v4f reads had row-stride 512 B == 0 mod 32 banks ->
// 4 rows alias onto 16 banks (16 acc/bank vs 8 minimum; 1.54M conflict
// cycles/dispatch). Store col c of row r at physical (c ^ ((r&1)*2))
// (16B-granular XOR) -> odd rows shift 4 banks -> uniform 8/bank.
// Pure storage permutation: values bit-identical, absmax 0.0 preserved.

#define WI 320
#define HI 320
#define NI 64
#define NZ (NI / 2)             // 32 image pairs
#define TWO 58                  // output cols per x-tile (64 loaded incl. halo)
#define GXD 6                   // ceil(320/58)
#define GYD 20                  // 16 output rows per block (4 waves x 4 rows)
#define NBLK (GXD * GYD * NZ)   // 3840 blocks
#define NPART (2 * NBLK)        // 7680 partial floats (2 images per block)
#define NPIX ((double)NI * WI * HI)
#define IMG (WI * HI)
#define WREG (5 * 4 * 64)       // per-wave LDS float2 count: 1280 (10240 B)

typedef float v2f __attribute__((ext_vector_type(2)));
typedef float v4f __attribute__((ext_vector_type(4)));

struct W7 { float w[7]; };

// One wave, one 58x4 strip of an image PAIR. XM: 0=left tile, 1=interior,
// 2=right. YI: all 10 input rows in-bounds. Returns packed SSIM partials.
template <bool YI, int XM>
__device__ __forceinline__ v2f wave_task(
    const float* __restrict__ X0, const float* __restrict__ X1,
    const float* __restrict__ Y0, const float* __restrict__ Y1,
    const W7& wv, v2f* __restrict__ vb, int x0, int y0, int lane)
{
    const int gx   = x0 + lane - 3;
    const bool xok = (XM == 1) || (XM == 0 ? (gx >= 0) : (gx < WI));

    // ---- 40 coalesced dword loads (lane = consecutive col), zero-pad OOB ----
    v2f xr[10], yr[10];
#pragma unroll
    for (int j = 0; j < 10; ++j) {
        const int gy  = y0 + j - 3;
        const bool ok = xok && (YI || ((unsigned)gy < (unsigned)HI));
        v2f xv = {0.f, 0.f}, yv = {0.f, 0.f};
        if (ok) {
            const int idx = gy * WI + gx;
            xv.x = X0[idx]; xv.y = X1[idx];
            yv.x = Y0[idx]; yv.y = Y1[idx];
        }
        xr[j] = xv; yr[j] = yv;
    }

    // ---- vertical 7-tap, 5 channels x 4 rows, packed over the image pair ----
    v2f acc[5][4];
#pragma unroll
    for (int ch = 0; ch < 5; ++ch)
#pragma unroll
        for (int r = 0; r < 4; ++r) acc[ch][r] = (v2f){0.f, 0.f};
#pragma unroll
    for (int j = 0; j < 10; ++j) {
        const v2f xv = xr[j], yv = yr[j];
        const v2f pxx = xv * xv, pyy = yv * yv, pxy = xv * yv;
#pragma unroll
        for (int r = 0; r < 4; ++r) {
            const int d = j - r;                 // compile-time predicate
            if (d >= 0 && d < 7) {
                const v2f w2 = {wv.w[d], wv.w[d]};
                acc[0][r] = __builtin_elementwise_fma(w2, xv,  acc[0][r]);
                acc[1][r] = __builtin_elementwise_fma(w2, yv,  acc[1][r]);
                acc[2][r] = __builtin_elementwise_fma(w2, pxx, acc[2][r]);
                acc[3][r] = __builtin_elementwise_fma(w2, pyy, acc[3][r]);
                acc[4][r] = __builtin_elementwise_fma(w2, pxy, acc[4][r]);
            }
        }
    }
    // 20 b64 writes; logical col=lane stored at physical lane^((r&1)*2).
    // Write banks stay a permutation per instruction -> uniform (free).
#pragma unroll
    for (int ch = 0; ch < 5; ++ch)
#pragma unroll
        for (int r = 0; r < 4; ++r)
            vb[ch * 256 + r * 64 + (lane ^ ((r & 1) * 2))] = acc[ch][r];

    __builtin_amdgcn_wave_barrier();   // scheduling fence; lgkmcnt orders the data

    // ---- horizontal 7-tap + SSIM. lane -> (row, 4 consecutive out cols) ----
    v2f lsum = {0.f, 0.f};
    const int row = lane >> 4;
    const int xg  = (lane & 15) << 2;          // 0,4,...,60
    if (xg < TWO) {                            // xg==60 lanes idle
        // Need f2[0..9] (j<=3, d<=6). f2[8..9] only matter for xg<=52 (at
        // xg=56 valid outputs j<2 use f2[0..7]); clamp that read in-bounds.
        const int xg3 = (xg > 52) ? 52 : xg;
        const int s   = (row & 1) * 2;         // 16B-block XOR (same as writes)
        const v2f zero = {0.f, 0.f};
        v2f m[4][5];
#pragma unroll
        for (int ch = 0; ch < 5; ++ch) {
            const v2f* base = &vb[ch * 256 + row * 64];
            const v4f q0 = *(const v4f*)&base[(xg     ) ^ s];
            const v4f q1 = *(const v4f*)&base[(xg +  2) ^ s];
            const v4f q2 = *(const v4f*)&base[(xg +  4) ^ s];
            const v4f q3 = *(const v4f*)&base[(xg +  6) ^ s];
            const v4f q4 = *(const v4f*)&base[(xg3 + 8) ^ s];
            const v2f f2[10] = {
                {q0.x,q0.y},{q0.z,q0.w},{q1.x,q1.y},{q1.z,q1.w},
                {q2.x,q2.y},{q2.z,q2.w},{q3.x,q3.y},{q3.z,q3.w},
                {q4.x,q4.y},{q4.z,q4.w}};
#pragma unroll
            for (int j = 0; j < 4; ++j) {
                v2f sum = zero;
#pragma unroll
                for (int d = 0; d < 7; ++d) {
                    const v2f w2 = {wv.w[d], wv.w[d]};
                    sum = __builtin_elementwise_fma(w2, f2[j + d], sum);
                }
                m[j][ch] = sum;
            }
        }
#pragma unroll
        for (int j = 0; j < 4; ++j) {
            const v2f mx = m[j][0], my = m[j][1];
            const v2f mxsq = mx * mx;
            const v2f mysq = my * my;
            const v2f mxy  = mx * my;
            const v2f vx   = (m[j][2] - mxsq) * 1.0208333333333333f;
            const v2f vy   = (m[j][3] - mysq) * 1.0208333333333333f;
            const v2f vxy  = (m[j][4] - mxy)  * 1.0208333333333333f;
            const v2f num  = (2.f * mxy + 0.0004f) * (2.f * vxy + 0.0036f);
            const v2f den  = (mxsq + mysq + 0.0004f) * (vx + vy + 0.0036f);
            v2f rden;
            rden.x = __builtin_amdgcn_rcpf(den.x);
            rden.y = __builtin_amdgcn_rcpf(den.y);
            const v2f term = num * rden;
            const bool valid = (xg + j < TWO) && (XM != 2 || x0 + xg + j < WI);
            lsum += valid ? term : zero;
        }
    }
    return lsum;
}

__global__ __launch_bounds__(256, 4) void ssim_kernel(
    const float* __restrict__ X, const float* __restrict__ Y,
    W7 wv, float* __restrict__ partial)
{
    __shared__ __align__(16) v2f vbuf[4 * WREG];   // exactly 40960 B -> 4 blocks/CU

    const int tid  = threadIdx.x;
    const int lane = tid & 63;
    const int w    = tid >> 6;
    const int x0   = blockIdx.x * TWO;
    const int y0   = blockIdx.y * 16 + w * 4;  // first output row of this wave
    const float* __restrict__ X0 = X + (size_t)(2 * blockIdx.z) * IMG;
    const float* __restrict__ X1 = X0 + IMG;
    const float* __restrict__ Y0 = Y + (size_t)(2 * blockIdx.z) * IMG;
    const float* __restrict__ Y1 = Y0 + IMG;
    v2f* vb = vbuf + w * WREG;

    const bool yi = (y0 >= 3) && (y0 <= HI - 7);  // all 10 input rows in-bounds
    const int  xm = (blockIdx.x == 0) ? 0 : ((blockIdx.x == GXD - 1) ? 2 : 1);

    v2f lsum;
    if (yi) {
        if      (xm == 0) lsum = wave_task<true, 0>(X0, X1, Y0, Y1, wv, vb, x0, y0, lane);
        else if (xm == 1) lsum = wave_task<true, 1>(X0, X1, Y0, Y1, wv, vb, x0, y0, lane);
        else              lsum = wave_task<true, 2>(X0, X1, Y0, Y1, wv, vb, x0, y0, lane);
    } else {
        if      (xm == 0) lsum = wave_task<false, 0>(X0, X1, Y0, Y1, wv, vb, x0, y0, lane);
        else if (xm == 1) lsum = wave_task<false, 1>(X0, X1, Y0, Y1, wv, vb, x0, y0, lane);
        else              lsum = wave_task<false, 2>(X0, X1, Y0, Y1, wv, vb, x0, y0, lane);
    }

    // ---- reduction: wave shuffle -> own (consumed) vbuf slot -> one barrier ----
#pragma unroll
    for (int off = 32; off > 0; off >>= 1) {
        lsum.x += __shfl_down(lsum.x, off, 64);
        lsum.y += __shfl_down(lsum.y, off, 64);
    }
    if (lane == 0) vb[0] = lsum;   // wave w writes only its own (consumed) region
    __syncthreads();
    if (tid == 0) {
        const int bid = (blockIdx.z * GYD + blockIdx.y) * GXD + blockIdx.x;
        const v2f t = (vbuf[0] + vbuf[WREG]) + (vbuf[2 * WREG] + vbuf[3 * WREG]);
        partial[2 * bid]     = t.x;
        partial[2 * bid + 1] = t.y;
    }
}

__global__ __launch_bounds__(256) void ssim_finalize(
    const float* __restrict__ partial, float* __restrict__ out)
{
    __shared__ double ws[4];
    const int tid = threadIdx.x;
    double s = 0.0;
    for (int i = tid; i < NPART; i += 256) s += (double)partial[i];
#pragma unroll
    for (int off = 32; off > 0; off >>= 1)
        s += __shfl_down(s, off, 64);
    if ((tid & 63) == 0) ws[tid >> 6] = s;
    __syncthreads();
    if (tid == 0)
        out[0] = (float)(1.0 - ((ws[0] + ws[1]) + (ws[2] + ws[3])) / NPIX);
}

extern "C" void kernel_launch(void* const* d_in, const int* in_sizes, int n_in,
                              void* d_out, int out_size, void* d_ws, size_t ws_size,
                              hipStream_t stream) {
    const float* X = (const float*)d_in[0];
    const float* Y = (const float*)d_in[1];
    // Exact 1D Gaussian weights in fp64 (7x7 window = outer product).
    W7 wv;
    {
        double g[7], s = 0.0;
        for (int i = 0; i < 7; ++i) {
            double x = (double)(i - 3);
            g[i] = exp(-(x * x) / (2.0 * 1.5 * 1.5));
            s += g[i];
        }
        for (int i = 0; i < 7; ++i) wv.w[i] = (float)(g[i] / s);
    }

    float* partial = (float*)d_ws;   // 7680 floats, fully written every launch

    dim3 grid(GXD, GYD, NZ);
    ssim_kernel<<<grid, 256, 0, stream>>>(X, Y, wv, partial);
    ssim_finalize<<<1, 256, 0, stream>>>(partial, (float*)d_out);
}